// Round 6
// baseline (554.899 us; speedup 1.0000x reference)
//
#include <hip/hip_runtime.h>

#define N_NODES 50000
#define E_EDGES 800000
#define E_TOT   (E_EDGES + N_NODES)   // edges + self loops
#define P_PAIRS 200000
#define IN_DIM  32
#define HID     64
#define HEADS   4
#define D       256
#define NEG_SLOPE 0.2f
#define SCAN_BS 1024
#define LOG2E 1.4426950408889634f

__device__ __forceinline__ float ex2(float v) { return __builtin_amdgcn_exp2f(v); }

__device__ __forceinline__ void edge_sd(const int* __restrict__ ei, int e, int& s, int& d) {
  if (e < E_EDGES) { s = ei[e]; d = ei[E_EDGES + e]; }
  else             { s = d = e - E_EDGES; }
}

// ================= CSR build (dst-grouped) =================
__global__ void count_k(const int* __restrict__ ei, int* __restrict__ deg) {
  int e = blockIdx.x * 256 + threadIdx.x;
  if (e >= E_TOT) return;
  int s, d; edge_sd(ei, e, s, d);
  atomicAdd(&deg[d], 1);
}

__global__ __launch_bounds__(SCAN_BS) void scan_block_k(const int* __restrict__ in,
                                                        int* __restrict__ out,
                                                        int* __restrict__ bsum, int n) {
  __shared__ int tmp[SCAN_BS];
  int g = blockIdx.x * SCAN_BS + threadIdx.x;
  tmp[threadIdx.x] = (g < n) ? in[g] : 0;
  __syncthreads();
  for (int off = 1; off < SCAN_BS; off <<= 1) {
    int t = 0;
    if ((int)threadIdx.x >= off) t = tmp[threadIdx.x - off];
    __syncthreads();
    if ((int)threadIdx.x >= off) tmp[threadIdx.x] += t;
    __syncthreads();
  }
  if (g < n) out[g] = tmp[threadIdx.x];
  if (threadIdx.x == SCAN_BS - 1) bsum[blockIdx.x] = tmp[SCAN_BS - 1];
}

__global__ void scan_top_k(int* __restrict__ bsum, int nb) {
  __shared__ int tmp[256];
  tmp[threadIdx.x] = ((int)threadIdx.x < nb) ? bsum[threadIdx.x] : 0;
  __syncthreads();
  for (int off = 1; off < 256; off <<= 1) {
    int t = 0;
    if ((int)threadIdx.x >= off) t = tmp[threadIdx.x - off];
    __syncthreads();
    if ((int)threadIdx.x >= off) tmp[threadIdx.x] += t;
    __syncthreads();
  }
  if ((int)threadIdx.x < nb) bsum[threadIdx.x] = tmp[threadIdx.x];
}

__global__ void add_off_k(const int* __restrict__ scan_out,
                          const int* __restrict__ bsum,
                          int* __restrict__ rowptr) {
  int g = blockIdx.x * 256 + threadIdx.x;
  if (g >= N_NODES) return;
  int blk = g / SCAN_BS;
  int add = blk ? bsum[blk - 1] : 0;
  rowptr[g + 1] = scan_out[g] + add;
  if (g == 0) rowptr[0] = 0;
}

__global__ void scatter_k(const int* __restrict__ ei,
                          const int* __restrict__ rowptr,
                          int* __restrict__ pos, int* __restrict__ csr) {
  int e = blockIdx.x * 256 + threadIdx.x;
  if (e >= E_TOT) return;
  int s, d; edge_sd(ei, e, s, d);
  int idx = rowptr[d] + atomicAdd(&pos[d], 1);
  csr[idx] = s;
}

// ================ layer-1 algebraic restructure ================
// Wa1[k][h] = sum_c W1[k, h*64+c] * att[h,c]  (pre-scaled by LOG2E)
__global__ void prep_wa1_k(const float* __restrict__ W1,
                           const float* __restrict__ as1,
                           const float* __restrict__ ad1,
                           float* __restrict__ wa_s, float* __restrict__ wa_d) {
  int t = threadIdx.x;                  // one block of 256
  int kk = (t >> 2) & 31, h = t & 3;
  const float* att = (t < 128) ? as1 : ad1;
  float sum = 0.f;
  for (int c = 0; c < HID; ++c) sum += W1[kk * D + h * HID + c] * att[h * HID + c];
  float* dst = (t < 128) ? wa_s : wa_d;
  dst[kk * 4 + h] = sum * LOG2E;
}

// alps1[n,h] = x[n] . wa_s[:,h] ; 8 lanes per node, 8 nodes per wave
__global__ __launch_bounds__(256) void alphas1_k(const float* __restrict__ x,
                                                 const float* __restrict__ wa_s,
                                                 const float* __restrict__ wa_d,
                                                 float* __restrict__ alps,
                                                 float* __restrict__ alpd) {
  int w = (blockIdx.x * 256 + threadIdx.x) >> 6;
  int lane = threadIdx.x & 63;
  int n = w * 8 + (lane >> 3);
  int j = lane & 7;
  float4 xv = make_float4(0.f, 0.f, 0.f, 0.f);
  if (n < N_NODES) xv = *(const float4*)(x + (size_t)n * IN_DIM + j * 4);
  float ps[4] = {0.f, 0.f, 0.f, 0.f}, pd[4] = {0.f, 0.f, 0.f, 0.f};
  #pragma unroll
  for (int kk = 0; kk < 4; ++kk) {
    float xk = ((const float*)&xv)[kk];
    float4 ws = *(const float4*)(wa_s + (j * 4 + kk) * 4);
    float4 wd = *(const float4*)(wa_d + (j * 4 + kk) * 4);
    ps[0] += xk * ws.x; ps[1] += xk * ws.y; ps[2] += xk * ws.z; ps[3] += xk * ws.w;
    pd[0] += xk * wd.x; pd[1] += xk * wd.y; pd[2] += xk * wd.z; pd[3] += xk * wd.w;
  }
  #pragma unroll
  for (int off = 1; off < 8; off <<= 1) {
    #pragma unroll
    for (int h = 0; h < 4; ++h) {
      ps[h] += __shfl_xor(ps[h], off);
      pd[h] += __shfl_xor(pd[h], off);
    }
  }
  if (j == 0 && n < N_NODES) {
    *(float4*)(alps + n * 4) = make_float4(ps[0], ps[1], ps[2], ps[3]);
    *(float4*)(alpd + n * 4) = make_float4(pd[0], pd[1], pd[2], pd[3]);
  }
}

// x-space gather: agg[n][h][k<32] = (sum_e exp2 w * x[src][k]) / den[h]
// half-wave (32 lanes) per node, lane = channel; all 4 heads in registers.
__global__ __launch_bounds__(256) void gat_gather1_k(
    const int* __restrict__ rowptr, const int* __restrict__ csr,
    const float* __restrict__ alps, const float* __restrict__ alpd,
    const float* __restrict__ x, float* __restrict__ agg) {
  int wid2 = (blockIdx.x * 256 + threadIdx.x) >> 6;
  int lane = threadIdx.x & 63;
  int half = lane >> 5, l = lane & 31;
  int n = wid2 * 2 + half;
  bool valid = n < N_NODES;
  int beg = valid ? rowptr[n] : 0;
  int end = valid ? rowptr[n + 1] : 0;
  float4 ad4 = make_float4(0.f, 0.f, 0.f, 0.f);
  if (valid) ad4 = *(const float4*)(alpd + n * 4);
  float m[4], den[4], acc[4];
  #pragma unroll
  for (int h = 0; h < 4; ++h) { m[h] = -1e30f; den[h] = 0.f; acc[h] = 0.f; }

  for (int i = beg; i < end; i += 4) {
    int s[4]; bool ok[4]; float4 al[4]; float xv[4];
    #pragma unroll
    for (int j = 0; j < 4; ++j) { ok[j] = (i + j) < end; s[j] = ok[j] ? csr[i + j] : 0; }
    #pragma unroll
    for (int j = 0; j < 4; ++j) al[j] = *(const float4*)(alps + s[j] * 4);
    #pragma unroll
    for (int j = 0; j < 4; ++j) xv[j] = x[(size_t)s[j] * IN_DIM + l];
    #pragma unroll
    for (int h = 0; h < 4; ++h) {
      float v[4];
      #pragma unroll
      for (int j = 0; j < 4; ++j) {
        float t = ((const float*)&al[j])[h] + ((const float*)&ad4)[h];
        t = fmaxf(t, NEG_SLOPE * t);
        v[j] = ok[j] ? t : -1e30f;
      }
      float mn = fmaxf(fmaxf(fmaxf(v[0], v[1]), fmaxf(v[2], v[3])), m[h]);
      float c  = ex2(m[h] - mn);
      float e0 = ex2(v[0] - mn), e1 = ex2(v[1] - mn);
      float e2 = ex2(v[2] - mn), e3 = ex2(v[3] - mn);
      den[h] = den[h] * c + (e0 + e1) + (e2 + e3);
      acc[h] = acc[h] * c + e0 * xv[0] + e1 * xv[1] + e2 * xv[2] + e3 * xv[3];
      m[h] = mn;
    }
  }
  if (valid) {
    #pragma unroll
    for (int h = 0; h < 4; ++h)
      agg[(size_t)n * 128 + h * 32 + l] = acc[h] / (den[h] + 1e-16f);
  }
}

// out1[n, q*64+c] = relu(agg[n,q,:] @ W1[:, q*64+c] + b1)
__global__ __launch_bounds__(256) void gemm_head1(const float* __restrict__ agg,
                                                  const float* __restrict__ W,
                                                  const float* __restrict__ b,
                                                  float* __restrict__ out) {
  __shared__ float As[32][68];
  __shared__ float Bs[32][64];
  const int row0 = blockIdx.x * 64;
  const int q = blockIdx.y;
  const int col0 = q * 64;
  const int t = threadIdx.x, tx = t & 15, ty = t >> 4;
  #pragma unroll
  for (int i = 0; i < 2; ++i) {
    int idx = t + i * 256;
    int r = idx >> 3, k4 = idx & 7;
    int rr = row0 + r;
    float4 a = make_float4(0.f, 0.f, 0.f, 0.f);
    if (rr < N_NODES) a = *(const float4*)(agg + (size_t)rr * 128 + q * 32 + k4 * 4);
    As[k4 * 4 + 0][r] = a.x;
    As[k4 * 4 + 1][r] = a.y;
    As[k4 * 4 + 2][r] = a.z;
    As[k4 * 4 + 3][r] = a.w;
  }
  #pragma unroll
  for (int i = 0; i < 2; ++i) {
    int idx = t + i * 256;
    int k = idx >> 4, c4 = idx & 15;
    *(float4*)&Bs[k][c4 * 4] = *(const float4*)(W + (size_t)k * D + col0 + c4 * 4);
  }
  __syncthreads();
  float acc[4][4] = {{0.f}};
  #pragma unroll
  for (int k = 0; k < 32; ++k) {
    float4 av = *(const float4*)&As[k][ty * 4];
    float4 bv = *(const float4*)&Bs[k][tx * 4];
    acc[0][0] += av.x * bv.x; acc[0][1] += av.x * bv.y;
    acc[0][2] += av.x * bv.z; acc[0][3] += av.x * bv.w;
    acc[1][0] += av.y * bv.x; acc[1][1] += av.y * bv.y;
    acc[1][2] += av.y * bv.z; acc[1][3] += av.y * bv.w;
    acc[2][0] += av.z * bv.x; acc[2][1] += av.z * bv.y;
    acc[2][2] += av.z * bv.z; acc[2][3] += av.z * bv.w;
    acc[3][0] += av.w * bv.x; acc[3][1] += av.w * bv.y;
    acc[3][2] += av.w * bv.z; acc[3][3] += av.w * bv.w;
  }
  float4 bv = *(const float4*)(b + col0 + tx * 4);
  #pragma unroll
  for (int i = 0; i < 4; ++i) {
    int rr = row0 + ty * 4 + i;
    if (rr < N_NODES) {
      float4 o;
      o.x = fmaxf(acc[i][0] + bv.x, 0.f);
      o.y = fmaxf(acc[i][1] + bv.y, 0.f);
      o.z = fmaxf(acc[i][2] + bv.z, 0.f);
      o.w = fmaxf(acc[i][3] + bv.w, 0.f);
      *(float4*)(out + (size_t)rr * D + col0 + tx * 4) = o;
    }
  }
}

// ===== layer-2 GEMM: 128x128 tile, 8x8 micro-tile (split quadrants), fused logits =====
// rows: {ty*4+i, 64+ty*4+i}; cols: {tx*4+j, 64+tx*4+j}  -> LDS reads <=2-way aliased
__global__ __launch_bounds__(256) void gemm2_k(const float* __restrict__ A,
                                               const float* __restrict__ W,
                                               const float* __restrict__ asrc,
                                               const float* __restrict__ adst,
                                               float* __restrict__ out,
                                               float* __restrict__ alps,
                                               float* __restrict__ alpd) {
  __shared__ float As[32][132];
  __shared__ float Bs[32][128];
  const int row0 = blockIdx.x * 128;
  const int col0 = blockIdx.y * 128;
  const int t = threadIdx.x, tx = t & 15, ty = t >> 4;
  float acc[8][8] = {{0.f}};

  for (int kc = 0; kc < D; kc += 32) {
    #pragma unroll
    for (int i = 0; i < 4; ++i) {
      int idx = t + i * 256;            // 0..1023
      int r = idx >> 3, k4 = idx & 7;
      int rr = row0 + r;
      float4 a = make_float4(0.f, 0.f, 0.f, 0.f);
      if (rr < N_NODES) a = *(const float4*)(A + (size_t)rr * D + kc + k4 * 4);
      As[k4 * 4 + 0][r] = a.x;
      As[k4 * 4 + 1][r] = a.y;
      As[k4 * 4 + 2][r] = a.z;
      As[k4 * 4 + 3][r] = a.w;
    }
    #pragma unroll
    for (int i = 0; i < 4; ++i) {
      int idx = t + i * 256;
      int k = idx >> 5, c4 = idx & 31;
      *(float4*)&Bs[k][c4 * 4] =
          *(const float4*)(W + (size_t)(kc + k) * D + col0 + c4 * 4);
    }
    __syncthreads();
    #pragma unroll
    for (int k = 0; k < 32; ++k) {
      float4 a0 = *(const float4*)&As[k][ty * 4];
      float4 a1 = *(const float4*)&As[k][64 + ty * 4];
      float4 b0 = *(const float4*)&Bs[k][tx * 4];
      float4 b1 = *(const float4*)&Bs[k][64 + tx * 4];
      const float* ar0 = (const float*)&a0; const float* ar1 = (const float*)&a1;
      const float* br0 = (const float*)&b0; const float* br1 = (const float*)&b1;
      #pragma unroll
      for (int i = 0; i < 4; ++i) {
        #pragma unroll
        for (int j = 0; j < 4; ++j) {
          acc[i][j]         += ar0[i] * br0[j];
          acc[i][j + 4]     += ar0[i] * br1[j];
          acc[i + 4][j]     += ar1[i] * br0[j];
          acc[i + 4][j + 4] += ar1[i] * br1[j];
        }
      }
    }
    __syncthreads();
  }

  // store h2 tile
  #pragma unroll
  for (int g = 0; g < 2; ++g) {
    #pragma unroll
    for (int i = 0; i < 4; ++i) {
      int rr = row0 + g * 64 + ty * 4 + i;
      if (rr < N_NODES) {
        *(float4*)(out + (size_t)rr * D + col0 + tx * 4) =
            make_float4(acc[g*4+i][0], acc[g*4+i][1], acc[g*4+i][2], acc[g*4+i][3]);
        *(float4*)(out + (size_t)rr * D + col0 + 64 + tx * 4) =
            make_float4(acc[g*4+i][4], acc[g*4+i][5], acc[g*4+i][6], acc[g*4+i][7]);
      }
    }
  }

  // fused attention logits (two heads per block: qA = cols[0:64), qB = cols[64:128))
  const int qA = blockIdx.y * 2, qB = qA + 1;
  float wsA[4], wdA[4], wsB[4], wdB[4];
  #pragma unroll
  for (int j = 0; j < 4; ++j) {
    wsA[j] = asrc[qA * HID + tx * 4 + j];  wdA[j] = adst[qA * HID + tx * 4 + j];
    wsB[j] = asrc[qB * HID + tx * 4 + j];  wdB[j] = adst[qB * HID + tx * 4 + j];
  }
  #pragma unroll
  for (int g = 0; g < 2; ++g) {
    #pragma unroll
    for (int i = 0; i < 4; ++i) {
      float psA = acc[g*4+i][0]*wsA[0] + acc[g*4+i][1]*wsA[1]
                + acc[g*4+i][2]*wsA[2] + acc[g*4+i][3]*wsA[3];
      float pdA = acc[g*4+i][0]*wdA[0] + acc[g*4+i][1]*wdA[1]
                + acc[g*4+i][2]*wdA[2] + acc[g*4+i][3]*wdA[3];
      float psB = acc[g*4+i][4]*wsB[0] + acc[g*4+i][5]*wsB[1]
                + acc[g*4+i][6]*wsB[2] + acc[g*4+i][7]*wsB[3];
      float pdB = acc[g*4+i][4]*wdB[0] + acc[g*4+i][5]*wdB[1]
                + acc[g*4+i][6]*wdB[2] + acc[g*4+i][7]*wdB[3];
      #pragma unroll
      for (int off = 1; off < 16; off <<= 1) {
        psA += __shfl_xor(psA, off);  pdA += __shfl_xor(pdA, off);
        psB += __shfl_xor(psB, off);  pdB += __shfl_xor(pdB, off);
      }
      int rr = row0 + g * 64 + ty * 4 + i;
      if (rr < N_NODES) {
        if (tx == 0)      { alps[rr*HEADS+qA] = psA*LOG2E; alpd[rr*HEADS+qA] = pdA*LOG2E; }
        else if (tx == 1) { alps[rr*HEADS+qB] = psB*LOG2E; alpd[rr*HEADS+qB] = pdB*LOG2E; }
      }
    }
  }
}

// ====== layer-2 gather with fused pair-head GEMV: one wave per node ======
// computes o = relu(softmax-agg + b2) in registers, then u=o.w0, v=o.w1 directly;
// the 256-wide h-output is never materialized.
__global__ __launch_bounds__(256) void gat_gather2_k(
    const int* __restrict__ rowptr, const int* __restrict__ csr,
    const float* __restrict__ alps, const float* __restrict__ alpd,
    const float* __restrict__ h, const float* __restrict__ b,
    const float* __restrict__ hw,
    float* __restrict__ u, float* __restrict__ v) {
  int wid = (blockIdx.x * 256 + threadIdx.x) >> 6;
  int lane = threadIdx.x & 63;
  if (wid >= N_NODES) return;
  int q = lane >> 4;
  int beg = rowptr[wid], end = rowptr[wid + 1];
  float ad = alpd[wid * HEADS + q];

  float m = -1e30f, den = 0.f;
  float4 acc = make_float4(0.f, 0.f, 0.f, 0.f);

  for (int i = beg; i < end; i += 6) {
    int s[6]; bool ok[6]; float xl[6]; float4 hv[6];
    #pragma unroll
    for (int j = 0; j < 6; ++j) { ok[j] = (i + j) < end; s[j] = ok[j] ? csr[i + j] : 0; }
    #pragma unroll
    for (int j = 0; j < 6; ++j) xl[j] = alps[s[j] * HEADS + q];
    #pragma unroll
    for (int j = 0; j < 6; ++j) hv[j] = *(const float4*)(h + (size_t)s[j] * D + lane * 4);
    float vv[6];
    #pragma unroll
    for (int j = 0; j < 6; ++j) {
      float t = xl[j] + ad;
      t = fmaxf(t, NEG_SLOPE * t);
      vv[j] = ok[j] ? t : -1e30f;
    }
    float mn = fmaxf(m, fmaxf(fmaxf(fmaxf(vv[0], vv[1]), fmaxf(vv[2], vv[3])),
                              fmaxf(vv[4], vv[5])));
    float c = ex2(m - mn);
    float e[6];
    #pragma unroll
    for (int j = 0; j < 6; ++j) e[j] = ex2(vv[j] - mn);
    den = den * c + ((e[0] + e[1]) + (e[2] + e[3])) + (e[4] + e[5]);
    acc.x = acc.x * c + e[0]*hv[0].x + e[1]*hv[1].x + e[2]*hv[2].x + e[3]*hv[3].x + e[4]*hv[4].x + e[5]*hv[5].x;
    acc.y = acc.y * c + e[0]*hv[0].y + e[1]*hv[1].y + e[2]*hv[2].y + e[3]*hv[3].y + e[4]*hv[4].y + e[5]*hv[5].y;
    acc.z = acc.z * c + e[0]*hv[0].z + e[1]*hv[1].z + e[2]*hv[2].z + e[3]*hv[3].z + e[4]*hv[4].z + e[5]*hv[5].z;
    acc.w = acc.w * c + e[0]*hv[0].w + e[1]*hv[1].w + e[2]*hv[2].w + e[3]*hv[3].w + e[4]*hv[4].w + e[5]*hv[5].w;
    m = mn;
  }

  float inv = 1.f / (den + 1e-16f);
  float4 bv = *(const float4*)(b + lane * 4);
  float4 o;
  o.x = fmaxf(acc.x * inv + bv.x, 0.f);
  o.y = fmaxf(acc.y * inv + bv.y, 0.f);
  o.z = fmaxf(acc.z * inv + bv.z, 0.f);
  o.w = fmaxf(acc.w * inv + bv.w, 0.f);

  // fused head GEMV: u = o . hw[0:256], v = o . hw[256:512] (per-lane 4 channels)
  float4 w0 = *(const float4*)(hw + lane * 4);
  float4 w1 = *(const float4*)(hw + D + lane * 4);
  float su = o.x * w0.x + o.y * w0.y + o.z * w0.z + o.w * w0.w;
  float sv = o.x * w1.x + o.y * w1.y + o.z * w1.z + o.w * w1.w;
  #pragma unroll
  for (int off = 32; off; off >>= 1) {
    su += __shfl_down(su, off);
    sv += __shfl_down(sv, off);
  }
  if (lane == 0) { u[wid] = su; v[wid] = sv; }
}

// ---- pair lookup: out[p] = u[a] + v[b] + hb ----
__global__ void pair_lu_k(const int* __restrict__ pairs,
                          const float* __restrict__ u, const float* __restrict__ v,
                          const float* __restrict__ hb, float* __restrict__ out) {
  int g = blockIdx.x * 256 + threadIdx.x;
  if (g >= P_PAIRS) return;
  int a = pairs[g * 2], b = pairs[g * 2 + 1];
  out[g] = u[a] + v[b] + hb[0];
}

extern "C" void kernel_launch(void* const* d_in, const int* in_sizes, int n_in,
                              void* d_out, int out_size, void* d_ws, size_t ws_size,
                              hipStream_t stream) {
  const float* x    = (const float*)d_in[0];
  const int*   ei   = (const int*)d_in[1];
  const int*   prs  = (const int*)d_in[2];
  const float* W1   = (const float*)d_in[3];
  const float* as1  = (const float*)d_in[4];
  const float* ad1  = (const float*)d_in[5];
  const float* b1   = (const float*)d_in[6];
  const float* W2   = (const float*)d_in[7];
  const float* as2  = (const float*)d_in[8];
  const float* ad2  = (const float*)d_in[9];
  const float* b2   = (const float*)d_in[10];
  const float* hw   = (const float*)d_in[11];
  const float* hb   = (const float*)d_in[12];
  float* out = (float*)d_out;

  char* w = (char*)d_ws;
  float* buf0 = (float*)w;            w += (size_t)N_NODES * D * 4;   // agg1 / h2
  float* buf1 = (float*)w;            w += (size_t)N_NODES * D * 4;   // out1
  float* alps = (float*)w;            w += (size_t)N_NODES * HEADS * 4;
  float* alpd = (float*)w;            w += (size_t)N_NODES * HEADS * 4;
  int* rowptr = (int*)w;              w += (size_t)(N_NODES + 1) * 4;
  int* csr    = (int*)w;              w += (size_t)E_TOT * 4;
  float* uu   = (float*)w;            w += (size_t)N_NODES * 4;
  float* vv   = (float*)w;            w += (size_t)N_NODES * 4;
  float* wa_s = (float*)w;            w += 128 * 4;
  float* wa_d = (float*)w;            w += 128 * 4;

  // CSR-build temporaries aliased into buf1 (first real write to buf1 is
  // gemm_head1, which runs strictly after scatter_k on this stream)
  int* deg      = (int*)buf1;
  int* scan_out = deg + N_NODES;
  int* bsum     = scan_out + N_NODES;

  const int eBlk     = (E_TOT + 255) / 256;               // 3321
  const int nScanBlk = (N_NODES + SCAN_BS - 1) / SCAN_BS; // 49
  const int nBlk256  = (N_NODES + 255) / 256;             // 196
  const int waveBlk  = (N_NODES * 64 + 255) / 256;        // 12500
  const int a1Blk    = (N_NODES * 8 + 255) / 256;         // 1563
  const int g1Blk    = ((N_NODES + 1) / 2 * 64 + 255) / 256; // 6250
  const int pairBlk  = (P_PAIRS + 255) / 256;             // 782
  const dim3 headGrid((N_NODES + 63) / 64, HEADS);        // 782 x 4 (K=32 GEMM)
  const dim3 g2Grid((N_NODES + 127) / 128, D / 128);      // 391 x 2

  // ---------- CSR build (once, reused by both layers) ----------
  hipMemsetAsync(deg, 0, (size_t)N_NODES * 4, stream);
  count_k<<<eBlk, 256, 0, stream>>>(ei, deg);
  scan_block_k<<<nScanBlk, SCAN_BS, 0, stream>>>(deg, scan_out, bsum, N_NODES);
  scan_top_k<<<1, 256, 0, stream>>>(bsum, nScanBlk);
  add_off_k<<<nBlk256, 256, 0, stream>>>(scan_out, bsum, rowptr);
  hipMemsetAsync(deg, 0, (size_t)N_NODES * 4, stream);   // reuse as pos
  scatter_k<<<eBlk, 256, 0, stream>>>(ei, rowptr, deg, csr);

  // ---------- layer 1 (x-space aggregation) ----------
  prep_wa1_k<<<1, 256, 0, stream>>>(W1, as1, ad1, wa_s, wa_d);
  alphas1_k<<<a1Blk, 256, 0, stream>>>(x, wa_s, wa_d, alps, alpd);
  gat_gather1_k<<<g1Blk, 256, 0, stream>>>(rowptr, csr, alps, alpd, x, buf0);
  gemm_head1<<<headGrid, 256, 0, stream>>>(buf0, W1, b1, buf1);

  // ---------- layer 2 ----------
  gemm2_k<<<g2Grid, 256, 0, stream>>>(buf1, W2, as2, ad2, buf0, alps, alpd);
  gat_gather2_k<<<waveBlk, 256, 0, stream>>>(rowptr, csr, alps, alpd, buf0, b2, hw, uu, vv);

  // ---------- pair head ----------
  pair_lu_k<<<pairBlk, 256, 0, stream>>>(prs, uu, vv, hb, out);
}

// Round 7
// 445.064 us; speedup vs baseline: 1.2468x; 1.2468x over previous
//
#include <hip/hip_runtime.h>

#define N_NODES 50000
#define E_EDGES 800000
#define E_TOT   (E_EDGES + N_NODES)   // edges + self loops
#define P_PAIRS 200000
#define IN_DIM  32
#define HID     64
#define HEADS   4
#define D       256
#define NEG_SLOPE 0.2f
#define SCAN_BS 1024
#define LOG2E 1.4426950408889634f

typedef short  s16x8 __attribute__((ext_vector_type(8)));
typedef float  f32x4 __attribute__((ext_vector_type(4)));

__device__ __forceinline__ float ex2(float v) { return __builtin_amdgcn_exp2f(v); }

__device__ __forceinline__ unsigned short bf16_rne(float f) {
  unsigned u = __float_as_uint(f);
  u += 0x7FFFu + ((u >> 16) & 1u);
  return (unsigned short)(u >> 16);
}
__device__ __forceinline__ float bf16f(unsigned short h) {
  return __uint_as_float(((unsigned)h) << 16);
}

__device__ __forceinline__ void edge_sd(const int* __restrict__ ei, int e, int& s, int& d) {
  if (e < E_EDGES) { s = ei[e]; d = ei[E_EDGES + e]; }
  else             { s = d = e - E_EDGES; }
}

// ================= CSR build (dst-grouped) =================
__global__ void count_k(const int* __restrict__ ei, int* __restrict__ deg) {
  int e = blockIdx.x * 256 + threadIdx.x;
  if (e >= E_TOT) return;
  int s, d; edge_sd(ei, e, s, d);
  atomicAdd(&deg[d], 1);
}

__global__ __launch_bounds__(SCAN_BS) void scan_block_k(const int* __restrict__ in,
                                                        int* __restrict__ out,
                                                        int* __restrict__ bsum, int n) {
  __shared__ int tmp[SCAN_BS];
  int g = blockIdx.x * SCAN_BS + threadIdx.x;
  tmp[threadIdx.x] = (g < n) ? in[g] : 0;
  __syncthreads();
  for (int off = 1; off < SCAN_BS; off <<= 1) {
    int t = 0;
    if ((int)threadIdx.x >= off) t = tmp[threadIdx.x - off];
    __syncthreads();
    if ((int)threadIdx.x >= off) tmp[threadIdx.x] += t;
    __syncthreads();
  }
  if (g < n) out[g] = tmp[threadIdx.x];
  if (threadIdx.x == SCAN_BS - 1) bsum[blockIdx.x] = tmp[SCAN_BS - 1];
}

__global__ void scan_top_k(int* __restrict__ bsum, int nb) {
  __shared__ int tmp[256];
  tmp[threadIdx.x] = ((int)threadIdx.x < nb) ? bsum[threadIdx.x] : 0;
  __syncthreads();
  for (int off = 1; off < 256; off <<= 1) {
    int t = 0;
    if ((int)threadIdx.x >= off) t = tmp[threadIdx.x - off];
    __syncthreads();
    if ((int)threadIdx.x >= off) tmp[threadIdx.x] += t;
    __syncthreads();
  }
  if ((int)threadIdx.x < nb) bsum[threadIdx.x] = tmp[threadIdx.x];
}

__global__ void add_off_k(const int* __restrict__ scan_out,
                          const int* __restrict__ bsum,
                          int* __restrict__ rowptr) {
  int g = blockIdx.x * 256 + threadIdx.x;
  if (g >= N_NODES) return;
  int blk = g / SCAN_BS;
  int add = blk ? bsum[blk - 1] : 0;
  rowptr[g + 1] = scan_out[g] + add;
  if (g == 0) rowptr[0] = 0;
}

__global__ void scatter_k(const int* __restrict__ ei,
                          const int* __restrict__ rowptr,
                          int* __restrict__ pos, int* __restrict__ csr) {
  int e = blockIdx.x * 256 + threadIdx.x;
  if (e >= E_TOT) return;
  int s, d; edge_sd(ei, e, s, d);
  int idx = rowptr[d] + atomicAdd(&pos[d], 1);
  csr[idx] = s;
}

// ================ layer-1 algebraic restructure ================
__global__ void prep_wa1_k(const float* __restrict__ W1,
                           const float* __restrict__ as1,
                           const float* __restrict__ ad1,
                           float* __restrict__ wa_s, float* __restrict__ wa_d) {
  int t = threadIdx.x;                  // one block of 256
  int kk = (t >> 2) & 31, h = t & 3;
  const float* att = (t < 128) ? as1 : ad1;
  float sum = 0.f;
  for (int c = 0; c < HID; ++c) sum += W1[kk * D + h * HID + c] * att[h * HID + c];
  float* dst = (t < 128) ? wa_s : wa_d;
  dst[kk * 4 + h] = sum * LOG2E;
}

// W2T split: Whi/Wlo[col][k] = bf16 split of W2[k][col]
__global__ void prep_w2t_k(const float* __restrict__ W2,
                           unsigned short* __restrict__ Whi,
                           unsigned short* __restrict__ Wlo) {
  int g = blockIdx.x * 256 + threadIdx.x;   // 65536
  int col = g >> 8, k = g & 255;
  float w = W2[(size_t)k * D + col];
  unsigned short hi = bf16_rne(w);
  unsigned short lo = bf16_rne(w - bf16f(hi));
  Whi[g] = hi;  Wlo[g] = lo;                // [col][k] flat
}

// alps1[n,h] = x[n] . wa_s[:,h] ; 8 lanes per node, 8 nodes per wave
__global__ __launch_bounds__(256) void alphas1_k(const float* __restrict__ x,
                                                 const float* __restrict__ wa_s,
                                                 const float* __restrict__ wa_d,
                                                 float* __restrict__ alps,
                                                 float* __restrict__ alpd) {
  int w = (blockIdx.x * 256 + threadIdx.x) >> 6;
  int lane = threadIdx.x & 63;
  int n = w * 8 + (lane >> 3);
  int j = lane & 7;
  float4 xv = make_float4(0.f, 0.f, 0.f, 0.f);
  if (n < N_NODES) xv = *(const float4*)(x + (size_t)n * IN_DIM + j * 4);
  float ps[4] = {0.f, 0.f, 0.f, 0.f}, pd[4] = {0.f, 0.f, 0.f, 0.f};
  #pragma unroll
  for (int kk = 0; kk < 4; ++kk) {
    float xk = ((const float*)&xv)[kk];
    float4 ws = *(const float4*)(wa_s + (j * 4 + kk) * 4);
    float4 wd = *(const float4*)(wa_d + (j * 4 + kk) * 4);
    ps[0] += xk * ws.x; ps[1] += xk * ws.y; ps[2] += xk * ws.z; ps[3] += xk * ws.w;
    pd[0] += xk * wd.x; pd[1] += xk * wd.y; pd[2] += xk * wd.z; pd[3] += xk * wd.w;
  }
  #pragma unroll
  for (int off = 1; off < 8; off <<= 1) {
    #pragma unroll
    for (int h = 0; h < 4; ++h) {
      ps[h] += __shfl_xor(ps[h], off);
      pd[h] += __shfl_xor(pd[h], off);
    }
  }
  if (j == 0 && n < N_NODES) {
    *(float4*)(alps + n * 4) = make_float4(ps[0], ps[1], ps[2], ps[3]);
    *(float4*)(alpd + n * 4) = make_float4(pd[0], pd[1], pd[2], pd[3]);
  }
}

// x-space gather: agg[n][h][k<32] = (sum_e exp2 w * x[src][k]) / den[h]
__global__ __launch_bounds__(256) void gat_gather1_k(
    const int* __restrict__ rowptr, const int* __restrict__ csr,
    const float* __restrict__ alps, const float* __restrict__ alpd,
    const float* __restrict__ x, float* __restrict__ agg) {
  int wid2 = (blockIdx.x * 256 + threadIdx.x) >> 6;
  int lane = threadIdx.x & 63;
  int half = lane >> 5, l = lane & 31;
  int n = wid2 * 2 + half;
  bool valid = n < N_NODES;
  int beg = valid ? rowptr[n] : 0;
  int end = valid ? rowptr[n + 1] : 0;
  float4 ad4 = make_float4(0.f, 0.f, 0.f, 0.f);
  if (valid) ad4 = *(const float4*)(alpd + n * 4);
  float m[4], den[4], acc[4];
  #pragma unroll
  for (int h = 0; h < 4; ++h) { m[h] = -1e30f; den[h] = 0.f; acc[h] = 0.f; }

  for (int i = beg; i < end; i += 4) {
    int s[4]; bool ok[4]; float4 al[4]; float xv[4];
    #pragma unroll
    for (int j = 0; j < 4; ++j) { ok[j] = (i + j) < end; s[j] = ok[j] ? csr[i + j] : 0; }
    #pragma unroll
    for (int j = 0; j < 4; ++j) al[j] = *(const float4*)(alps + s[j] * 4);
    #pragma unroll
    for (int j = 0; j < 4; ++j) xv[j] = x[(size_t)s[j] * IN_DIM + l];
    #pragma unroll
    for (int h = 0; h < 4; ++h) {
      float v[4];
      #pragma unroll
      for (int j = 0; j < 4; ++j) {
        float t = ((const float*)&al[j])[h] + ((const float*)&ad4)[h];
        t = fmaxf(t, NEG_SLOPE * t);
        v[j] = ok[j] ? t : -1e30f;
      }
      float mn = fmaxf(fmaxf(fmaxf(v[0], v[1]), fmaxf(v[2], v[3])), m[h]);
      float c  = ex2(m[h] - mn);
      float e0 = ex2(v[0] - mn), e1 = ex2(v[1] - mn);
      float e2 = ex2(v[2] - mn), e3 = ex2(v[3] - mn);
      den[h] = den[h] * c + (e0 + e1) + (e2 + e3);
      acc[h] = acc[h] * c + e0 * xv[0] + e1 * xv[1] + e2 * xv[2] + e3 * xv[3];
      m[h] = mn;
    }
  }
  if (valid) {
    #pragma unroll
    for (int h = 0; h < 4; ++h)
      agg[(size_t)n * 128 + h * 32 + l] = acc[h] / (den[h] + 1e-16f);
  }
}

// out1 = relu(agg @ W1_head + b1), emitted as SPLIT bf16 (hi/lo) for the MFMA gemm
__global__ __launch_bounds__(256) void gemm_head1(const float* __restrict__ agg,
                                                  const float* __restrict__ W,
                                                  const float* __restrict__ b,
                                                  unsigned short* __restrict__ Ahi,
                                                  unsigned short* __restrict__ Alo) {
  __shared__ float As[32][68];
  __shared__ float Bs[32][64];
  const int row0 = blockIdx.x * 64;
  const int q = blockIdx.y;
  const int col0 = q * 64;
  const int t = threadIdx.x, tx = t & 15, ty = t >> 4;
  #pragma unroll
  for (int i = 0; i < 2; ++i) {
    int idx = t + i * 256;
    int r = idx >> 3, k4 = idx & 7;
    int rr = row0 + r;
    float4 a = make_float4(0.f, 0.f, 0.f, 0.f);
    if (rr < N_NODES) a = *(const float4*)(agg + (size_t)rr * 128 + q * 32 + k4 * 4);
    As[k4 * 4 + 0][r] = a.x;
    As[k4 * 4 + 1][r] = a.y;
    As[k4 * 4 + 2][r] = a.z;
    As[k4 * 4 + 3][r] = a.w;
  }
  #pragma unroll
  for (int i = 0; i < 2; ++i) {
    int idx = t + i * 256;
    int k = idx >> 4, c4 = idx & 15;
    *(float4*)&Bs[k][c4 * 4] = *(const float4*)(W + (size_t)k * D + col0 + c4 * 4);
  }
  __syncthreads();
  float acc[4][4] = {{0.f}};
  #pragma unroll
  for (int k = 0; k < 32; ++k) {
    float4 av = *(const float4*)&As[k][ty * 4];
    float4 bv = *(const float4*)&Bs[k][tx * 4];
    acc[0][0] += av.x * bv.x; acc[0][1] += av.x * bv.y;
    acc[0][2] += av.x * bv.z; acc[0][3] += av.x * bv.w;
    acc[1][0] += av.y * bv.x; acc[1][1] += av.y * bv.y;
    acc[1][2] += av.y * bv.z; acc[1][3] += av.y * bv.w;
    acc[2][0] += av.z * bv.x; acc[2][1] += av.z * bv.y;
    acc[2][2] += av.z * bv.z; acc[2][3] += av.z * bv.w;
    acc[3][0] += av.w * bv.x; acc[3][1] += av.w * bv.y;
    acc[3][2] += av.w * bv.z; acc[3][3] += av.w * bv.w;
  }
  float4 bv = *(const float4*)(b + col0 + tx * 4);
  const float bb[4] = {bv.x, bv.y, bv.z, bv.w};
  #pragma unroll
  for (int i = 0; i < 4; ++i) {
    int rr = row0 + ty * 4 + i;
    if (rr < N_NODES) {
      ushort4 hi, lo;
      unsigned short* hp = (unsigned short*)&hi;
      unsigned short* lp = (unsigned short*)&lo;
      #pragma unroll
      for (int j = 0; j < 4; ++j) {
        float o = fmaxf(acc[i][j] + bb[j], 0.f);
        unsigned short h = bf16_rne(o);
        hp[j] = h;
        lp[j] = bf16_rne(o - bf16f(h));
      }
      *(ushort4*)(Ahi + (size_t)rr * D + col0 + tx * 4) = hi;
      *(ushort4*)(Alo + (size_t)rr * D + col0 + tx * 4) = lo;
    }
  }
}

// ===== layer-2 GEMM via split-bf16 MFMA (3 products ~= fp32 precision) =====
// 128x128 tile / block (4 waves, each 64x64). mfma_f32_16x16x32_bf16.
// A frag: row = lane&15, k = (lane>>4)*8+j ; B frag: col = lane&15 (from [col][k] LDS);
// C/D: col = lane&15, row = (lane>>4)*4 + reg   [verified m89]
__global__ __launch_bounds__(256) void gemm2_mfma(
    const unsigned short* __restrict__ Ahi, const unsigned short* __restrict__ Alo,
    const unsigned short* __restrict__ Whi, const unsigned short* __restrict__ Wlo,
    const float* __restrict__ asrc, const float* __restrict__ adst,
    float* __restrict__ h2, float* __restrict__ alps, float* __restrict__ alpd) {
  __shared__ __attribute__((aligned(16))) unsigned short As_hi[128][40];
  __shared__ __attribute__((aligned(16))) unsigned short As_lo[128][40];
  __shared__ __attribute__((aligned(16))) unsigned short Bs_hi[128][40];
  __shared__ __attribute__((aligned(16))) unsigned short Bs_lo[128][40];
  const int row0 = blockIdx.x * 128;
  const int col0 = blockIdx.y * 128;
  const int t = threadIdx.x;
  const int wave = t >> 6, lane = t & 63;
  const int wr = wave >> 1, wc = wave & 1;
  const int lg = lane >> 4, li = lane & 15;

  f32x4 acc[4][4];
  #pragma unroll
  for (int m = 0; m < 4; ++m)
    #pragma unroll
    for (int n = 0; n < 4; ++n) acc[m][n] = (f32x4)0.f;

  for (int kc = 0; kc < D; kc += 32) {
    #pragma unroll
    for (int i = 0; i < 2; ++i) {
      int idx = t + i * 256;          // 0..511
      int r = idx >> 2, seg = idx & 3;
      int rr = row0 + r;
      uint4 vh = make_uint4(0, 0, 0, 0), vl = make_uint4(0, 0, 0, 0);
      if (rr < N_NODES) {
        vh = *(const uint4*)(Ahi + (size_t)rr * D + kc + seg * 8);
        vl = *(const uint4*)(Alo + (size_t)rr * D + kc + seg * 8);
      }
      *(uint4*)&As_hi[r][seg * 8] = vh;
      *(uint4*)&As_lo[r][seg * 8] = vl;
      // B: W2T[col][k], no guard needed (256 cols exactly)
      uint4 wh = *(const uint4*)(Whi + (size_t)(col0 + r) * D + kc + seg * 8);
      uint4 wl = *(const uint4*)(Wlo + (size_t)(col0 + r) * D + kc + seg * 8);
      *(uint4*)&Bs_hi[r][seg * 8] = wh;
      *(uint4*)&Bs_lo[r][seg * 8] = wl;
    }
    __syncthreads();
    s16x8 ah[4], al[4], bh[4], bl[4];
    #pragma unroll
    for (int m = 0; m < 4; ++m) {
      int r = wr * 64 + m * 16 + li;
      ah[m] = *(const s16x8*)&As_hi[r][lg * 8];
      al[m] = *(const s16x8*)&As_lo[r][lg * 8];
    }
    #pragma unroll
    for (int n = 0; n < 4; ++n) {
      int c = wc * 64 + n * 16 + li;
      bh[n] = *(const s16x8*)&Bs_hi[c][lg * 8];
      bl[n] = *(const s16x8*)&Bs_lo[c][lg * 8];
    }
    #pragma unroll
    for (int m = 0; m < 4; ++m) {
      #pragma unroll
      for (int n = 0; n < 4; ++n) {
        acc[m][n] = __builtin_amdgcn_mfma_f32_16x16x32_bf16(ah[m], bh[n], acc[m][n], 0, 0, 0);
        acc[m][n] = __builtin_amdgcn_mfma_f32_16x16x32_bf16(ah[m], bl[n], acc[m][n], 0, 0, 0);
        acc[m][n] = __builtin_amdgcn_mfma_f32_16x16x32_bf16(al[m], bh[n], acc[m][n], 0, 0, 0);
      }
    }
    __syncthreads();
  }

  // store h2 tile
  #pragma unroll
  for (int m = 0; m < 4; ++m) {
    #pragma unroll
    for (int reg = 0; reg < 4; ++reg) {
      int rr = row0 + wr * 64 + m * 16 + lg * 4 + reg;
      if (rr < N_NODES) {
        #pragma unroll
        for (int n = 0; n < 4; ++n)
          h2[(size_t)rr * D + col0 + wc * 64 + n * 16 + li] = acc[m][n][reg];
      }
    }
  }

  // fused attention logits: this wave's 64 cols == one head q
  const int q = blockIdx.y * 2 + wc;
  float wsv[4], wdv[4];
  #pragma unroll
  for (int n = 0; n < 4; ++n) {
    wsv[n] = asrc[q * HID + n * 16 + li];
    wdv[n] = adst[q * HID + n * 16 + li];
  }
  #pragma unroll
  for (int m = 0; m < 4; ++m) {
    #pragma unroll
    for (int reg = 0; reg < 4; ++reg) {
      float ps = acc[m][0][reg] * wsv[0] + acc[m][1][reg] * wsv[1]
               + acc[m][2][reg] * wsv[2] + acc[m][3][reg] * wsv[3];
      float pd = acc[m][0][reg] * wdv[0] + acc[m][1][reg] * wdv[1]
               + acc[m][2][reg] * wdv[2] + acc[m][3][reg] * wdv[3];
      #pragma unroll
      for (int off = 1; off < 16; off <<= 1) {
        ps += __shfl_xor(ps, off);
        pd += __shfl_xor(pd, off);
      }
      int rr = row0 + wr * 64 + m * 16 + lg * 4 + reg;
      if (li == 0 && rr < N_NODES) {
        alps[rr * HEADS + q] = ps * LOG2E;
        alpd[rr * HEADS + q] = pd * LOG2E;
      }
    }
  }
}

// ====== layer-2 gather with fused pair-head GEMV: one wave per node ======
__global__ __launch_bounds__(256) void gat_gather2_k(
    const int* __restrict__ rowptr, const int* __restrict__ csr,
    const float* __restrict__ alps, const float* __restrict__ alpd,
    const float* __restrict__ h, const float* __restrict__ b,
    const float* __restrict__ hw,
    float* __restrict__ u, float* __restrict__ v) {
  int wid = (blockIdx.x * 256 + threadIdx.x) >> 6;
  int lane = threadIdx.x & 63;
  if (wid >= N_NODES) return;
  int q = lane >> 4;
  int beg = rowptr[wid], end = rowptr[wid + 1];
  float ad = alpd[wid * HEADS + q];

  float m = -1e30f, den = 0.f;
  float4 acc = make_float4(0.f, 0.f, 0.f, 0.f);

  for (int i = beg; i < end; i += 6) {
    int s[6]; bool ok[6]; float xl[6]; float4 hv[6];
    #pragma unroll
    for (int j = 0; j < 6; ++j) { ok[j] = (i + j) < end; s[j] = ok[j] ? csr[i + j] : 0; }
    #pragma unroll
    for (int j = 0; j < 6; ++j) xl[j] = alps[s[j] * HEADS + q];
    #pragma unroll
    for (int j = 0; j < 6; ++j) hv[j] = *(const float4*)(h + (size_t)s[j] * D + lane * 4);
    float vv[6];
    #pragma unroll
    for (int j = 0; j < 6; ++j) {
      float t = xl[j] + ad;
      t = fmaxf(t, NEG_SLOPE * t);
      vv[j] = ok[j] ? t : -1e30f;
    }
    float mn = fmaxf(m, fmaxf(fmaxf(fmaxf(vv[0], vv[1]), fmaxf(vv[2], vv[3])),
                              fmaxf(vv[4], vv[5])));
    float c = ex2(m - mn);
    float e[6];
    #pragma unroll
    for (int j = 0; j < 6; ++j) e[j] = ex2(vv[j] - mn);
    den = den * c + ((e[0] + e[1]) + (e[2] + e[3])) + (e[4] + e[5]);
    acc.x = acc.x * c + e[0]*hv[0].x + e[1]*hv[1].x + e[2]*hv[2].x + e[3]*hv[3].x + e[4]*hv[4].x + e[5]*hv[5].x;
    acc.y = acc.y * c + e[0]*hv[0].y + e[1]*hv[1].y + e[2]*hv[2].y + e[3]*hv[3].y + e[4]*hv[4].y + e[5]*hv[5].y;
    acc.z = acc.z * c + e[0]*hv[0].z + e[1]*hv[1].z + e[2]*hv[2].z + e[3]*hv[3].z + e[4]*hv[4].z + e[5]*hv[5].z;
    acc.w = acc.w * c + e[0]*hv[0].w + e[1]*hv[1].w + e[2]*hv[2].w + e[3]*hv[3].w + e[4]*hv[4].w + e[5]*hv[5].w;
    m = mn;
  }

  float inv = 1.f / (den + 1e-16f);
  float4 bv = *(const float4*)(b + lane * 4);
  float4 o;
  o.x = fmaxf(acc.x * inv + bv.x, 0.f);
  o.y = fmaxf(acc.y * inv + bv.y, 0.f);
  o.z = fmaxf(acc.z * inv + bv.z, 0.f);
  o.w = fmaxf(acc.w * inv + bv.w, 0.f);

  float4 w0 = *(const float4*)(hw + lane * 4);
  float4 w1 = *(const float4*)(hw + D + lane * 4);
  float su = o.x * w0.x + o.y * w0.y + o.z * w0.z + o.w * w0.w;
  float sv = o.x * w1.x + o.y * w1.y + o.z * w1.z + o.w * w1.w;
  #pragma unroll
  for (int off = 32; off; off >>= 1) {
    su += __shfl_down(su, off);
    sv += __shfl_down(sv, off);
  }
  if (lane == 0) { u[wid] = su; v[wid] = sv; }
}

// ---- pair lookup: out[p] = u[a] + v[b] + hb ----
__global__ void pair_lu_k(const int* __restrict__ pairs,
                          const float* __restrict__ u, const float* __restrict__ v,
                          const float* __restrict__ hb, float* __restrict__ out) {
  int g = blockIdx.x * 256 + threadIdx.x;
  if (g >= P_PAIRS) return;
  int a = pairs[g * 2], b = pairs[g * 2 + 1];
  out[g] = u[a] + v[b] + hb[0];
}

extern "C" void kernel_launch(void* const* d_in, const int* in_sizes, int n_in,
                              void* d_out, int out_size, void* d_ws, size_t ws_size,
                              hipStream_t stream) {
  const float* x    = (const float*)d_in[0];
  const int*   ei   = (const int*)d_in[1];
  const int*   prs  = (const int*)d_in[2];
  const float* W1   = (const float*)d_in[3];
  const float* as1  = (const float*)d_in[4];
  const float* ad1  = (const float*)d_in[5];
  const float* b1   = (const float*)d_in[6];
  const float* W2   = (const float*)d_in[7];
  const float* as2  = (const float*)d_in[8];
  const float* ad2  = (const float*)d_in[9];
  const float* b2   = (const float*)d_in[10];
  const float* hw   = (const float*)d_in[11];
  const float* hb   = (const float*)d_in[12];
  float* out = (float*)d_out;

  const int NPAD = 50048;   // 391*128

  char* w = (char*)d_ws;
  float* buf0 = (float*)w;             w += (size_t)N_NODES * D * 4;     // agg1 [n][128] then h2 [n][256]
  float* alps = (float*)w;             w += (size_t)N_NODES * HEADS * 4;
  float* alpd = (float*)w;             w += (size_t)N_NODES * HEADS * 4;
  int* rowptr = (int*)w;               w += (size_t)(N_NODES + 1) * 4;
  int* csr    = (int*)w;               w += (size_t)E_TOT * 4;
  float* uu   = (float*)w;             w += (size_t)N_NODES * 4;
  float* vv   = (float*)w;             w += (size_t)N_NODES * 4;
  float* wa_s = (float*)w;             w += 128 * 4;
  float* wa_d = (float*)w;             w += 128 * 4;
  unsigned short* Ahi = (unsigned short*)w;  w += (size_t)NPAD * D * 2;  // out1 bf16 hi
  unsigned short* Alo = (unsigned short*)w;  w += (size_t)NPAD * D * 2;  // out1 bf16 lo
  unsigned short* Whi = (unsigned short*)w;  w += (size_t)D * D * 2;     // W2T hi
  unsigned short* Wlo = (unsigned short*)w;  w += (size_t)D * D * 2;     // W2T lo

  // CSR-build temporaries aliased into buf0 (first real write to buf0 is
  // gat_gather1_k, which runs strictly after scatter_k on this stream)
  int* deg      = (int*)buf0;
  int* scan_out = deg + N_NODES;
  int* bsum     = scan_out + N_NODES;

  const int eBlk     = (E_TOT + 255) / 256;               // 3321
  const int nScanBlk = (N_NODES + SCAN_BS - 1) / SCAN_BS; // 49
  const int nBlk256  = (N_NODES + 255) / 256;             // 196
  const int waveBlk  = (N_NODES * 64 + 255) / 256;        // 12500
  const int a1Blk    = (N_NODES * 8 + 255) / 256;         // 1563
  const int g1Blk    = ((N_NODES + 1) / 2 * 64 + 255) / 256; // 6250
  const int pairBlk  = (P_PAIRS + 255) / 256;             // 782
  const dim3 headGrid((N_NODES + 63) / 64, HEADS);        // 782 x 4 (K=32 GEMM)
  const dim3 mfmaGrid(NPAD / 128, D / 128);               // 391 x 2

  // ---------- CSR build (once, reused by both layers) ----------
  hipMemsetAsync(deg, 0, (size_t)N_NODES * 4, stream);
  count_k<<<eBlk, 256, 0, stream>>>(ei, deg);
  scan_block_k<<<nScanBlk, SCAN_BS, 0, stream>>>(deg, scan_out, bsum, N_NODES);
  scan_top_k<<<1, 256, 0, stream>>>(bsum, nScanBlk);
  add_off_k<<<nBlk256, 256, 0, stream>>>(scan_out, bsum, rowptr);
  hipMemsetAsync(deg, 0, (size_t)N_NODES * 4, stream);   // reuse as pos
  scatter_k<<<eBlk, 256, 0, stream>>>(ei, rowptr, deg, csr);

  // ---------- weight prep ----------
  prep_wa1_k<<<1, 256, 0, stream>>>(W1, as1, ad1, wa_s, wa_d);
  prep_w2t_k<<<D * D / 256, 256, 0, stream>>>(W2, Whi, Wlo);

  // ---------- layer 1 (x-space aggregation) ----------
  alphas1_k<<<a1Blk, 256, 0, stream>>>(x, wa_s, wa_d, alps, alpd);
  gat_gather1_k<<<g1Blk, 256, 0, stream>>>(rowptr, csr, alps, alpd, x, buf0);
  gemm_head1<<<headGrid, 256, 0, stream>>>(buf0, W1, b1, Ahi, Alo);

  // ---------- layer 2 (split-bf16 MFMA GEMM + gather w/ fused pair head) ----------
  gemm2_mfma<<<mfmaGrid, 256, 0, stream>>>(Ahi, Alo, Whi, Wlo, as2, ad2,
                                           buf0, alps, alpd);
  gat_gather2_k<<<waveBlk, 256, 0, stream>>>(rowptr, csr, alps, alpd, buf0, b2, hw, uu, vv);

  // ---------- pair head ----------
  pair_lu_k<<<pairBlk, 256, 0, stream>>>(prs, uu, vv, hb, out);
}

// Round 10
// 391.818 us; speedup vs baseline: 1.4162x; 1.1359x over previous
//
#include <hip/hip_runtime.h>

#define N_NODES 50000
#define E_EDGES 800000
#define E_TOT   (E_EDGES + N_NODES)   // edges + self loops
#define P_PAIRS 200000
#define IN_DIM  32
#define HID     64
#define HEADS   4
#define D       256
#define NEG_SLOPE 0.2f
#define SCAN_BS 1024
#define LOG2E 1.4426950408889634f

typedef short    s16x8 __attribute__((ext_vector_type(8)));
typedef float    f32x4 __attribute__((ext_vector_type(4)));
typedef _Float16 f16x4 __attribute__((ext_vector_type(4)));

__device__ __forceinline__ float ex2(float v) { return __builtin_amdgcn_exp2f(v); }

__device__ __forceinline__ unsigned short bf16_rne(float f) {
  unsigned u = __float_as_uint(f);
  u += 0x7FFFu + ((u >> 16) & 1u);
  return (unsigned short)(u >> 16);
}
__device__ __forceinline__ float bf16f(unsigned short h) {
  return __uint_as_float(((unsigned)h) << 16);
}

__device__ __forceinline__ void edge_sd(const int* __restrict__ ei, int e, int& s, int& d) {
  if (e < E_EDGES) { s = ei[e]; d = ei[E_EDGES + e]; }
  else             { s = d = e - E_EDGES; }
}

// ================= CSR build (dst-grouped) =================
__global__ void count_k(const int* __restrict__ ei, int* __restrict__ deg) {
  int e = blockIdx.x * 256 + threadIdx.x;
  if (e >= E_TOT) return;
  int s, d; edge_sd(ei, e, s, d);
  atomicAdd(&deg[d], 1);
}

__global__ __launch_bounds__(SCAN_BS) void scan_block_k(const int* __restrict__ in,
                                                        int* __restrict__ out,
                                                        int* __restrict__ bsum, int n) {
  __shared__ int tmp[SCAN_BS];
  int g = blockIdx.x * SCAN_BS + threadIdx.x;
  tmp[threadIdx.x] = (g < n) ? in[g] : 0;
  __syncthreads();
  for (int off = 1; off < SCAN_BS; off <<= 1) {
    int t = 0;
    if ((int)threadIdx.x >= off) t = tmp[threadIdx.x - off];
    __syncthreads();
    if ((int)threadIdx.x >= off) tmp[threadIdx.x] += t;
    __syncthreads();
  }
  if (g < n) out[g] = tmp[threadIdx.x];
  if (threadIdx.x == SCAN_BS - 1) bsum[blockIdx.x] = tmp[SCAN_BS - 1];
}

__global__ void scan_top_k(int* __restrict__ bsum, int nb) {
  __shared__ int tmp[256];
  tmp[threadIdx.x] = ((int)threadIdx.x < nb) ? bsum[threadIdx.x] : 0;
  __syncthreads();
  for (int off = 1; off < 256; off <<= 1) {
    int t = 0;
    if ((int)threadIdx.x >= off) t = tmp[threadIdx.x - off];
    __syncthreads();
    if ((int)threadIdx.x >= off) tmp[threadIdx.x] += t;
    __syncthreads();
  }
  if ((int)threadIdx.x < nb) bsum[threadIdx.x] = tmp[threadIdx.x];
}

__global__ void add_off_k(const int* __restrict__ scan_out,
                          const int* __restrict__ bsum,
                          int* __restrict__ rowptr) {
  int g = blockIdx.x * 256 + threadIdx.x;
  if (g >= N_NODES) return;
  int blk = g / SCAN_BS;
  int add = blk ? bsum[blk - 1] : 0;
  rowptr[g + 1] = scan_out[g] + add;
  if (g == 0) rowptr[0] = 0;
}

__global__ void scatter_k(const int* __restrict__ ei,
                          const int* __restrict__ rowptr,
                          int* __restrict__ pos, int* __restrict__ csr) {
  int e = blockIdx.x * 256 + threadIdx.x;
  if (e >= E_TOT) return;
  int s, d; edge_sd(ei, e, s, d);
  int idx = rowptr[d] + atomicAdd(&pos[d], 1);
  csr[idx] = s;
}

// ================ layer-1 algebraic restructure ================
__global__ void prep_wa1_k(const float* __restrict__ W1,
                           const float* __restrict__ as1,
                           const float* __restrict__ ad1,
                           float* __restrict__ wa_s, float* __restrict__ wa_d) {
  int t = threadIdx.x;                  // one block of 256
  int kk = (t >> 2) & 31, h = t & 3;
  const float* att = (t < 128) ? as1 : ad1;
  float sum = 0.f;
  for (int c = 0; c < HID; ++c) sum += W1[kk * D + h * HID + c] * att[h * HID + c];
  float* dst = (t < 128) ? wa_s : wa_d;
  dst[kk * 4 + h] = sum * LOG2E;
}

// W2T split: Whi/Wlo[col][k] = bf16 split of W2[k][col]
__global__ void prep_w2t_k(const float* __restrict__ W2,
                           unsigned short* __restrict__ Whi,
                           unsigned short* __restrict__ Wlo) {
  int g = blockIdx.x * 256 + threadIdx.x;   // 65536
  int col = g >> 8, k = g & 255;
  float w = W2[(size_t)k * D + col];
  unsigned short hi = bf16_rne(w);
  unsigned short lo = bf16_rne(w - bf16f(hi));
  Whi[g] = hi;  Wlo[g] = lo;                // [col][k] flat
}

// alps1[n,h] = x[n] . wa_s[:,h] ; 8 lanes per node, 8 nodes per wave
__global__ __launch_bounds__(256) void alphas1_k(const float* __restrict__ x,
                                                 const float* __restrict__ wa_s,
                                                 const float* __restrict__ wa_d,
                                                 float* __restrict__ alps,
                                                 float* __restrict__ alpd) {
  int w = (blockIdx.x * 256 + threadIdx.x) >> 6;
  int lane = threadIdx.x & 63;
  int n = w * 8 + (lane >> 3);
  int j = lane & 7;
  float4 xv = make_float4(0.f, 0.f, 0.f, 0.f);
  if (n < N_NODES) xv = *(const float4*)(x + (size_t)n * IN_DIM + j * 4);
  float ps[4] = {0.f, 0.f, 0.f, 0.f}, pd[4] = {0.f, 0.f, 0.f, 0.f};
  #pragma unroll
  for (int kk = 0; kk < 4; ++kk) {
    float xk = ((const float*)&xv)[kk];
    float4 ws = *(const float4*)(wa_s + (j * 4 + kk) * 4);
    float4 wd = *(const float4*)(wa_d + (j * 4 + kk) * 4);
    ps[0] += xk * ws.x; ps[1] += xk * ws.y; ps[2] += xk * ws.z; ps[3] += xk * ws.w;
    pd[0] += xk * wd.x; pd[1] += xk * wd.y; pd[2] += xk * wd.z; pd[3] += xk * wd.w;
  }
  #pragma unroll
  for (int off = 1; off < 8; off <<= 1) {
    #pragma unroll
    for (int h = 0; h < 4; ++h) {
      ps[h] += __shfl_xor(ps[h], off);
      pd[h] += __shfl_xor(pd[h], off);
    }
  }
  if (j == 0 && n < N_NODES) {
    *(float4*)(alps + n * 4) = make_float4(ps[0], ps[1], ps[2], ps[3]);
    *(float4*)(alpd + n * 4) = make_float4(pd[0], pd[1], pd[2], pd[3]);
  }
}

// x-space gather: agg[n][h][k<32] = (sum_e exp2 w * x[src][k]) / den[h]
__global__ __launch_bounds__(256) void gat_gather1_k(
    const int* __restrict__ rowptr, const int* __restrict__ csr,
    const float* __restrict__ alps, const float* __restrict__ alpd,
    const float* __restrict__ x, float* __restrict__ agg) {
  int wid2 = (blockIdx.x * 256 + threadIdx.x) >> 6;
  int lane = threadIdx.x & 63;
  int half = lane >> 5, l = lane & 31;
  int n = wid2 * 2 + half;
  bool valid = n < N_NODES;
  int beg = valid ? rowptr[n] : 0;
  int end = valid ? rowptr[n + 1] : 0;
  float4 ad4 = make_float4(0.f, 0.f, 0.f, 0.f);
  if (valid) ad4 = *(const float4*)(alpd + n * 4);
  float m[4], den[4], acc[4];
  #pragma unroll
  for (int h = 0; h < 4; ++h) { m[h] = -1e30f; den[h] = 0.f; acc[h] = 0.f; }

  for (int i = beg; i < end; i += 4) {
    int s[4]; bool ok[4]; float4 al[4]; float xv[4];
    #pragma unroll
    for (int j = 0; j < 4; ++j) { ok[j] = (i + j) < end; s[j] = ok[j] ? csr[i + j] : 0; }
    #pragma unroll
    for (int j = 0; j < 4; ++j) al[j] = *(const float4*)(alps + s[j] * 4);
    #pragma unroll
    for (int j = 0; j < 4; ++j) xv[j] = x[(size_t)s[j] * IN_DIM + l];
    #pragma unroll
    for (int h = 0; h < 4; ++h) {
      float v[4];
      #pragma unroll
      for (int j = 0; j < 4; ++j) {
        float t = ((const float*)&al[j])[h] + ((const float*)&ad4)[h];
        t = fmaxf(t, NEG_SLOPE * t);
        v[j] = ok[j] ? t : -1e30f;
      }
      float mn = fmaxf(fmaxf(fmaxf(v[0], v[1]), fmaxf(v[2], v[3])), m[h]);
      float c  = ex2(m[h] - mn);
      float e0 = ex2(v[0] - mn), e1 = ex2(v[1] - mn);
      float e2 = ex2(v[2] - mn), e3 = ex2(v[3] - mn);
      den[h] = den[h] * c + (e0 + e1) + (e2 + e3);
      acc[h] = acc[h] * c + e0 * xv[0] + e1 * xv[1] + e2 * xv[2] + e3 * xv[3];
      m[h] = mn;
    }
  }
  if (valid) {
    #pragma unroll
    for (int h = 0; h < 4; ++h)
      agg[(size_t)n * 128 + h * 32 + l] = acc[h] / (den[h] + 1e-16f);
  }
}

// out1 = relu(agg @ W1_head + b1), emitted as SPLIT bf16 (hi/lo) for the MFMA gemm
__global__ __launch_bounds__(256) void gemm_head1(const float* __restrict__ agg,
                                                  const float* __restrict__ W,
                                                  const float* __restrict__ b,
                                                  unsigned short* __restrict__ Ahi,
                                                  unsigned short* __restrict__ Alo) {
  __shared__ float As[32][68];
  __shared__ float Bs[32][64];
  const int row0 = blockIdx.x * 64;
  const int q = blockIdx.y;
  const int col0 = q * 64;
  const int t = threadIdx.x, tx = t & 15, ty = t >> 4;
  #pragma unroll
  for (int i = 0; i < 2; ++i) {
    int idx = t + i * 256;
    int r = idx >> 3, k4 = idx & 7;
    int rr = row0 + r;
    float4 a = make_float4(0.f, 0.f, 0.f, 0.f);
    if (rr < N_NODES) a = *(const float4*)(agg + (size_t)rr * 128 + q * 32 + k4 * 4);
    As[k4 * 4 + 0][r] = a.x;
    As[k4 * 4 + 1][r] = a.y;
    As[k4 * 4 + 2][r] = a.z;
    As[k4 * 4 + 3][r] = a.w;
  }
  #pragma unroll
  for (int i = 0; i < 2; ++i) {
    int idx = t + i * 256;
    int k = idx >> 4, c4 = idx & 15;
    *(float4*)&Bs[k][c4 * 4] = *(const float4*)(W + (size_t)k * D + col0 + c4 * 4);
  }
  __syncthreads();
  float acc[4][4] = {{0.f}};
  #pragma unroll
  for (int k = 0; k < 32; ++k) {
    float4 av = *(const float4*)&As[k][ty * 4];
    float4 bv = *(const float4*)&Bs[k][tx * 4];
    acc[0][0] += av.x * bv.x; acc[0][1] += av.x * bv.y;
    acc[0][2] += av.x * bv.z; acc[0][3] += av.x * bv.w;
    acc[1][0] += av.y * bv.x; acc[1][1] += av.y * bv.y;
    acc[1][2] += av.y * bv.z; acc[1][3] += av.y * bv.w;
    acc[2][0] += av.z * bv.x; acc[2][1] += av.z * bv.y;
    acc[2][2] += av.z * bv.z; acc[2][3] += av.z * bv.w;
    acc[3][0] += av.w * bv.x; acc[3][1] += av.w * bv.y;
    acc[3][2] += av.w * bv.z; acc[3][3] += av.w * bv.w;
  }
  float4 bv = *(const float4*)(b + col0 + tx * 4);
  const float bb[4] = {bv.x, bv.y, bv.z, bv.w};
  #pragma unroll
  for (int i = 0; i < 4; ++i) {
    int rr = row0 + ty * 4 + i;
    if (rr < N_NODES) {
      ushort4 hi, lo;
      unsigned short* hp = (unsigned short*)&hi;
      unsigned short* lp = (unsigned short*)&lo;
      #pragma unroll
      for (int j = 0; j < 4; ++j) {
        float o = fmaxf(acc[i][j] + bb[j], 0.f);
        unsigned short h = bf16_rne(o);
        hp[j] = h;
        lp[j] = bf16_rne(o - bf16f(h));
      }
      *(ushort4*)(Ahi + (size_t)rr * D + col0 + tx * 4) = hi;
      *(ushort4*)(Alo + (size_t)rr * D + col0 + tx * 4) = lo;
    }
  }
}

// ===== layer-2 GEMM via split-bf16 MFMA; h2 emitted as fp16 for the gather =====
__global__ __launch_bounds__(256) void gemm2_mfma(
    const unsigned short* __restrict__ Ahi, const unsigned short* __restrict__ Alo,
    const unsigned short* __restrict__ Whi, const unsigned short* __restrict__ Wlo,
    const float* __restrict__ asrc, const float* __restrict__ adst,
    _Float16* __restrict__ h2, float* __restrict__ alps, float* __restrict__ alpd) {
  __shared__ __attribute__((aligned(16))) unsigned short As_hi[128][40];
  __shared__ __attribute__((aligned(16))) unsigned short As_lo[128][40];
  __shared__ __attribute__((aligned(16))) unsigned short Bs_hi[128][40];
  __shared__ __attribute__((aligned(16))) unsigned short Bs_lo[128][40];
  const int row0 = blockIdx.x * 128;
  const int col0 = blockIdx.y * 128;
  const int t = threadIdx.x;
  const int wave = t >> 6, lane = t & 63;
  const int wr = wave >> 1, wc = wave & 1;
  const int lg = lane >> 4, li = lane & 15;

  f32x4 acc[4][4];
  #pragma unroll
  for (int m = 0; m < 4; ++m)
    #pragma unroll
    for (int n = 0; n < 4; ++n) acc[m][n] = (f32x4)0.f;

  for (int kc = 0; kc < D; kc += 32) {
    #pragma unroll
    for (int i = 0; i < 2; ++i) {
      int idx = t + i * 256;          // 0..511
      int r = idx >> 2, seg = idx & 3;
      int rr = row0 + r;
      uint4 vh = make_uint4(0, 0, 0, 0), vl = make_uint4(0, 0, 0, 0);
      if (rr < N_NODES) {
        vh = *(const uint4*)(Ahi + (size_t)rr * D + kc + seg * 8);
        vl = *(const uint4*)(Alo + (size_t)rr * D + kc + seg * 8);
      }
      *(uint4*)&As_hi[r][seg * 8] = vh;
      *(uint4*)&As_lo[r][seg * 8] = vl;
      uint4 wh = *(const uint4*)(Whi + (size_t)(col0 + r) * D + kc + seg * 8);
      uint4 wl = *(const uint4*)(Wlo + (size_t)(col0 + r) * D + kc + seg * 8);
      *(uint4*)&Bs_hi[r][seg * 8] = wh;
      *(uint4*)&Bs_lo[r][seg * 8] = wl;
    }
    __syncthreads();
    s16x8 ah[4], al[4], bh[4], bl[4];
    #pragma unroll
    for (int m = 0; m < 4; ++m) {
      int r = wr * 64 + m * 16 + li;
      ah[m] = *(const s16x8*)&As_hi[r][lg * 8];
      al[m] = *(const s16x8*)&As_lo[r][lg * 8];
    }
    #pragma unroll
    for (int n = 0; n < 4; ++n) {
      int c = wc * 64 + n * 16 + li;
      bh[n] = *(const s16x8*)&Bs_hi[c][lg * 8];
      bl[n] = *(const s16x8*)&Bs_lo[c][lg * 8];
    }
    #pragma unroll
    for (int m = 0; m < 4; ++m) {
      #pragma unroll
      for (int n = 0; n < 4; ++n) {
        acc[m][n] = __builtin_amdgcn_mfma_f32_16x16x32_bf16(ah[m], bh[n], acc[m][n], 0, 0, 0);
        acc[m][n] = __builtin_amdgcn_mfma_f32_16x16x32_bf16(ah[m], bl[n], acc[m][n], 0, 0, 0);
        acc[m][n] = __builtin_amdgcn_mfma_f32_16x16x32_bf16(al[m], bh[n], acc[m][n], 0, 0, 0);
      }
    }
    __syncthreads();
  }

  // store h2 tile as fp16
  #pragma unroll
  for (int m = 0; m < 4; ++m) {
    #pragma unroll
    for (int reg = 0; reg < 4; ++reg) {
      int rr = row0 + wr * 64 + m * 16 + lg * 4 + reg;
      if (rr < N_NODES) {
        #pragma unroll
        for (int n = 0; n < 4; ++n)
          h2[(size_t)rr * D + col0 + wc * 64 + n * 16 + li] = (_Float16)acc[m][n][reg];
      }
    }
  }

  // fused attention logits (fp32 accumulators): this wave's 64 cols == head q
  const int q = blockIdx.y * 2 + wc;
  float wsv[4], wdv[4];
  #pragma unroll
  for (int n = 0; n < 4; ++n) {
    wsv[n] = asrc[q * HID + n * 16 + li];
    wdv[n] = adst[q * HID + n * 16 + li];
  }
  #pragma unroll
  for (int m = 0; m < 4; ++m) {
    #pragma unroll
    for (int reg = 0; reg < 4; ++reg) {
      float ps = acc[m][0][reg] * wsv[0] + acc[m][1][reg] * wsv[1]
               + acc[m][2][reg] * wsv[2] + acc[m][3][reg] * wsv[3];
      float pd = acc[m][0][reg] * wdv[0] + acc[m][1][reg] * wdv[1]
               + acc[m][2][reg] * wdv[2] + acc[m][3][reg] * wdv[3];
      #pragma unroll
      for (int off = 1; off < 16; off <<= 1) {
        ps += __shfl_xor(ps, off);
        pd += __shfl_xor(pd, off);
      }
      int rr = row0 + wr * 64 + m * 16 + lg * 4 + reg;
      if (li == 0 && rr < N_NODES) {
        alps[rr * HEADS + q] = ps * LOG2E;
        alpd[rr * HEADS + q] = pd * LOG2E;
      }
    }
  }
}

// ====== layer-2 gather (fp16 h rows) with fused pair-head GEMV ======
__global__ __launch_bounds__(256) void gat_gather2_k(
    const int* __restrict__ rowptr, const int* __restrict__ csr,
    const float* __restrict__ alps, const float* __restrict__ alpd,
    const _Float16* __restrict__ h, const float* __restrict__ b,
    const float* __restrict__ hw,
    float* __restrict__ u, float* __restrict__ v) {
  int wid = (blockIdx.x * 256 + threadIdx.x) >> 6;
  int lane = threadIdx.x & 63;
  if (wid >= N_NODES) return;
  int q = lane >> 4;
  int beg = rowptr[wid], end = rowptr[wid + 1];
  float ad = alpd[wid * HEADS + q];

  float m = -1e30f, den = 0.f;
  float4 acc = make_float4(0.f, 0.f, 0.f, 0.f);

  for (int i = beg; i < end; i += 6) {
    int s[6]; bool ok[6]; float xl[6]; f16x4 hv[6];
    #pragma unroll
    for (int j = 0; j < 6; ++j) { ok[j] = (i + j) < end; s[j] = ok[j] ? csr[i + j] : 0; }
    #pragma unroll
    for (int j = 0; j < 6; ++j) xl[j] = alps[s[j] * HEADS + q];
    #pragma unroll
    for (int j = 0; j < 6; ++j) hv[j] = *(const f16x4*)(h + (size_t)s[j] * D + lane * 4);
    float vv[6];
    #pragma unroll
    for (int j = 0; j < 6; ++j) {
      float t = xl[j] + ad;
      t = fmaxf(t, NEG_SLOPE * t);
      vv[j] = ok[j] ? t : -1e30f;
    }
    float mn = fmaxf(m, fmaxf(fmaxf(fmaxf(vv[0], vv[1]), fmaxf(vv[2], vv[3])),
                              fmaxf(vv[4], vv[5])));
    float c = ex2(m - mn);
    float e[6];
    #pragma unroll
    for (int j = 0; j < 6; ++j) e[j] = ex2(vv[j] - mn);
    den = den * c + ((e[0] + e[1]) + (e[2] + e[3])) + (e[4] + e[5]);
    acc.x = acc.x * c + e[0]*(float)hv[0].x + e[1]*(float)hv[1].x + e[2]*(float)hv[2].x
                      + e[3]*(float)hv[3].x + e[4]*(float)hv[4].x + e[5]*(float)hv[5].x;
    acc.y = acc.y * c + e[0]*(float)hv[0].y + e[1]*(float)hv[1].y + e[2]*(float)hv[2].y
                      + e[3]*(float)hv[3].y + e[4]*(float)hv[4].y + e[5]*(float)hv[5].y;
    acc.z = acc.z * c + e[0]*(float)hv[0].z + e[1]*(float)hv[1].z + e[2]*(float)hv[2].z
                      + e[3]*(float)hv[3].z + e[4]*(float)hv[4].z + e[5]*(float)hv[5].z;
    acc.w = acc.w * c + e[0]*(float)hv[0].w + e[1]*(float)hv[1].w + e[2]*(float)hv[2].w
                      + e[3]*(float)hv[3].w + e[4]*(float)hv[4].w + e[5]*(float)hv[5].w;
    m = mn;
  }

  float inv = 1.f / (den + 1e-16f);
  float4 bv = *(const float4*)(b + lane * 4);
  float4 o;
  o.x = fmaxf(acc.x * inv + bv.x, 0.f);
  o.y = fmaxf(acc.y * inv + bv.y, 0.f);
  o.z = fmaxf(acc.z * inv + bv.z, 0.f);
  o.w = fmaxf(acc.w * inv + bv.w, 0.f);

  float4 w0 = *(const float4*)(hw + lane * 4);
  float4 w1 = *(const float4*)(hw + D + lane * 4);
  float su = o.x * w0.x + o.y * w0.y + o.z * w0.z + o.w * w0.w;
  float sv = o.x * w1.x + o.y * w1.y + o.z * w1.z + o.w * w1.w;
  #pragma unroll
  for (int off = 32; off; off >>= 1) {
    su += __shfl_down(su, off);
    sv += __shfl_down(sv, off);
  }
  if (lane == 0) { u[wid] = su; v[wid] = sv; }
}

// ---- pair lookup: out[p] = u[a] + v[b] + hb ----
__global__ void pair_lu_k(const int* __restrict__ pairs,
                          const float* __restrict__ u, const float* __restrict__ v,
                          const float* __restrict__ hb, float* __restrict__ out) {
  int g = blockIdx.x * 256 + threadIdx.x;
  if (g >= P_PAIRS) return;
  int a = pairs[g * 2], b = pairs[g * 2 + 1];
  out[g] = u[a] + v[b] + hb[0];
}

extern "C" void kernel_launch(void* const* d_in, const int* in_sizes, int n_in,
                              void* d_out, int out_size, void* d_ws, size_t ws_size,
                              hipStream_t stream) {
  const float* x    = (const float*)d_in[0];
  const int*   ei   = (const int*)d_in[1];
  const int*   prs  = (const int*)d_in[2];
  const float* W1   = (const float*)d_in[3];
  const float* as1  = (const float*)d_in[4];
  const float* ad1  = (const float*)d_in[5];
  const float* b1   = (const float*)d_in[6];
  const float* W2   = (const float*)d_in[7];
  const float* as2  = (const float*)d_in[8];
  const float* ad2  = (const float*)d_in[9];
  const float* b2   = (const float*)d_in[10];
  const float* hw   = (const float*)d_in[11];
  const float* hb   = (const float*)d_in[12];
  float* out = (float*)d_out;

  const int NPAD = 50048;   // 391*128

  char* w = (char*)d_ws;
  float* buf0 = (float*)w;             w += (size_t)N_NODES * D * 4;     // agg1 [n][128] / h2 fp16 [n][256]
  float* alps = (float*)w;             w += (size_t)N_NODES * HEADS * 4;
  float* alpd = (float*)w;             w += (size_t)N_NODES * HEADS * 4;
  int* rowptr = (int*)w;               w += (size_t)(N_NODES + 1) * 4;
  int* csr    = (int*)w;               w += (size_t)E_TOT * 4;
  float* uu   = (float*)w;             w += (size_t)N_NODES * 4;
  float* vv   = (float*)w;             w += (size_t)N_NODES * 4;
  float* wa_s = (float*)w;             w += 128 * 4;
  float* wa_d = (float*)w;             w += 128 * 4;
  unsigned short* Ahi = (unsigned short*)w;  w += (size_t)NPAD * D * 2;  // out1 bf16 hi
  unsigned short* Alo = (unsigned short*)w;  w += (size_t)NPAD * D * 2;  // out1 bf16 lo
  unsigned short* Whi = (unsigned short*)w;  w += (size_t)D * D * 2;     // W2T hi
  unsigned short* Wlo = (unsigned short*)w;  w += (size_t)D * D * 2;     // W2T lo

  _Float16* h2f16 = (_Float16*)buf0;

  // CSR-build temporaries aliased into buf0 (first real write to buf0 is
  // gat_gather1_k, which runs strictly after scatter_k on this stream)
  int* deg      = (int*)buf0;
  int* scan_out = deg + N_NODES;
  int* bsum     = scan_out + N_NODES;

  const int eBlk     = (E_TOT + 255) / 256;               // 3321
  const int nScanBlk = (N_NODES + SCAN_BS - 1) / SCAN_BS; // 49
  const int nBlk256  = (N_NODES + 255) / 256;             // 196
  const int waveBlk  = (N_NODES * 64 + 255) / 256;        // 12500
  const int a1Blk    = (N_NODES * 8 + 255) / 256;         // 1563
  const int g1Blk    = ((N_NODES + 1) / 2 * 64 + 255) / 256; // 6250
  const int pairBlk  = (P_PAIRS + 255) / 256;             // 782
  const dim3 headGrid((N_NODES + 63) / 64, HEADS);        // 782 x 4 (K=32 GEMM)
  const dim3 mfmaGrid(NPAD / 128, D / 128);               // 391 x 2

  // ---------- CSR build (once, reused by both layers) ----------
  hipMemsetAsync(deg, 0, (size_t)N_NODES * 4, stream);
  count_k<<<eBlk, 256, 0, stream>>>(ei, deg);
  scan_block_k<<<nScanBlk, SCAN_BS, 0, stream>>>(deg, scan_out, bsum, N_NODES);
  scan_top_k<<<1, 256, 0, stream>>>(bsum, nScanBlk);
  add_off_k<<<nBlk256, 256, 0, stream>>>(scan_out, bsum, rowptr);
  hipMemsetAsync(deg, 0, (size_t)N_NODES * 4, stream);   // reuse as pos
  scatter_k<<<eBlk, 256, 0, stream>>>(ei, rowptr, deg, csr);

  // ---------- weight prep ----------
  prep_wa1_k<<<1, 256, 0, stream>>>(W1, as1, ad1, wa_s, wa_d);
  prep_w2t_k<<<D * D / 256, 256, 0, stream>>>(W2, Whi, Wlo);

  // ---------- layer 1 (x-space aggregation) ----------
  alphas1_k<<<a1Blk, 256, 0, stream>>>(x, wa_s, wa_d, alps, alpd);
  gat_gather1_k<<<g1Blk, 256, 0, stream>>>(rowptr, csr, alps, alpd, x, buf0);
  gemm_head1<<<headGrid, 256, 0, stream>>>(buf0, W1, b1, Ahi, Alo);

  // ---------- layer 2 (split-bf16 MFMA GEMM + fp16 gather w/ fused pair head) ----------
  gemm2_mfma<<<mfmaGrid, 256, 0, stream>>>(Ahi, Alo, Whi, Wlo, as2, ad2,
                                           h2f16, alps, alpd);
  gat_gather2_k<<<waveBlk, 256, 0, stream>>>(rowptr, csr, alps, alpd, h2f16, b2, hw, uu, vv);

  // ---------- pair head ----------
  pair_lu_k<<<pairBlk, 256, 0, stream>>>(prs, uu, vv, hb, out);
}